// Round 8
// baseline (172.478 us; speedup 1.0000x reference)
//
#include <hip/hip_runtime.h>
#include <math.h>
#include <stdint.h>

// out = sum_j W[j] * (sum_n |yt[n,j]-yp[n,j]|) / (sum_n yt[n,j])
// (outer mean's 1/N cancels the 1/N inside col_mean)
//
// R8: nt loads (R7's win: 65 -> <49us; L2 no-allocate broke the 2.6 TB/s
// wall) + compiler-proof 10-deep load clustering. Loads issued as
// asm volatile global_load_dwordx4 ... nt (volatile asm preserves mutual
// order), then ONE s_waitcnt vmcnt(0) asm tying all 10 results via "+v" —
// the scheduler cannot narrow the window to 2-3 loads as it did in R2-R4
// (VGPR_Count 28-36 every time).
//
// Column math (R2): float4 q = tid + k*TTH, component c -> col (4q+c)%5;
// 4*TTH mod 5 == 2 -> col = (c + 2k + 4*tid)%5. (c+2k)%5 static after
// unroll; per-thread rotation un-done once at the end through LDS.

#define GRID 2048
#define BLOCK 256
#define TTH (GRID * BLOCK)  // 524288 threads; 4*TTH mod 5 == 2
#define KLOADS 10           // 524288*10 = 5242880 float4s per array, exact
#define BAT 5               // k's per batch: 10 dwordx4 nt loads in flight

typedef float vf4 __attribute__((ext_vector_type(4)));

__global__ __launch_bounds__(BLOCK) void regress_reduce_fast(
    const float* __restrict__ yt, const float* __restrict__ yp,
    float* __restrict__ partials) {
  const int tid = blockIdx.x * BLOCK + threadIdx.x;
  const uint32_t base = (uint32_t)tid * 16u;  // byte offset of this thread's float4

  // rotated-space accumulators: local m corresponds to column (m + 4*tid)%5
  float s[5] = {0.f, 0.f, 0.f, 0.f, 0.f};
  float a[5] = {0.f, 0.f, 0.f, 0.f, 0.f};

  vf4 t[BAT], p[BAT];

#pragma unroll
  for (int b = 0; b < KLOADS / BAT; ++b) {
    // ---- issue: 10 nt dwordx4 loads, order locked by asm volatile ----
#pragma unroll
    for (int j = 0; j < BAT; ++j) {
      const uint32_t off = base + (uint32_t)((b * BAT + j) * (TTH * 16));
      asm volatile("global_load_dwordx4 %0, %1, %2 nt"
                   : "=v"(t[j]) : "v"(off), "s"(yt));
      asm volatile("global_load_dwordx4 %0, %1, %2 nt"
                   : "=v"(p[j]) : "v"(off), "s"(yp));
    }
    // ---- single wait; "+v" ties force all 10 results live across it ----
    asm volatile("s_waitcnt vmcnt(0)"
                 : "+v"(t[0]), "+v"(t[1]), "+v"(t[2]), "+v"(t[3]), "+v"(t[4]),
                   "+v"(p[0]), "+v"(p[1]), "+v"(p[2]), "+v"(p[3]), "+v"(p[4]));
    // ---- consume ----
#pragma unroll
    for (int j = 0; j < BAT; ++j) {
      const int k = b * BAT + j;
      const int m0 = (2 * k + 0) % 5;  // static after unroll
      const int m1 = (2 * k + 1) % 5;
      const int m2 = (2 * k + 2) % 5;
      const int m3 = (2 * k + 3) % 5;
      s[m0] += t[j].x; a[m0] += fabsf(t[j].x - p[j].x);
      s[m1] += t[j].y; a[m1] += fabsf(t[j].y - p[j].y);
      s[m2] += t[j].z; a[m2] += fabsf(t[j].z - p[j].z);
      s[m3] += t[j].w; a[m3] += fabsf(t[j].w - p[j].w);
    }
  }

  // un-rotate into global column space + block reduction via LDS
  __shared__ float red[BLOCK][11];  // +1 pad
  const int tix = threadIdx.x;
  const int rr = tid % 5;
#pragma unroll
  for (int m = 0; m < 5; ++m) {
    int g = m - rr; if (g < 0) g += 5;
    red[tix][g] = s[m];
    red[tix][5 + g] = a[m];
  }
  __syncthreads();
#pragma unroll
  for (int off = BLOCK / 2; off > 0; off >>= 1) {
    if (tix < off) {
#pragma unroll
      for (int v = 0; v < 10; ++v) red[tix][v] += red[tix + off][v];
    }
    __syncthreads();
  }
  if (tix < 10) partials[blockIdx.x * 10 + tix] = red[0][tix];  // deterministic
}

// generic fallback (any nrows), correctness-first
__global__ __launch_bounds__(BLOCK) void regress_reduce_generic(
    const float* __restrict__ yt, const float* __restrict__ yp,
    float* __restrict__ partials, long long nrows) {
  float s[5] = {0.f, 0.f, 0.f, 0.f, 0.f};
  float a[5] = {0.f, 0.f, 0.f, 0.f, 0.f};
  const long long tid = (long long)blockIdx.x * blockDim.x + threadIdx.x;
  const long long stride = (long long)gridDim.x * blockDim.x;
  for (long long r = tid; r < nrows; r += stride) {
#pragma unroll
    for (int c = 0; c < 5; ++c) {
      float tv = yt[r * 5 + c];
      s[c] += tv;
      a[c] += fabsf(tv - yp[r * 5 + c]);
    }
  }
  __shared__ float red[BLOCK][11];
  const int t = threadIdx.x;
#pragma unroll
  for (int c = 0; c < 5; ++c) { red[t][c] = s[c]; red[t][5 + c] = a[c]; }
  __syncthreads();
#pragma unroll
  for (int off = BLOCK / 2; off > 0; off >>= 1) {
    if (t < off) {
#pragma unroll
      for (int v = 0; v < 10; ++v) red[t][v] += red[t + off][v];
    }
    __syncthreads();
  }
  if (t < 10) partials[blockIdx.x * 10 + t] = red[0][t];
}

__global__ __launch_bounds__(256) void regress_finalize(
    const float* __restrict__ partials, int nblocks, float* __restrict__ out) {
  float acc[10] = {0.f, 0.f, 0.f, 0.f, 0.f, 0.f, 0.f, 0.f, 0.f, 0.f};
  for (int b = threadIdx.x; b < nblocks; b += 256) {
#pragma unroll
    for (int v = 0; v < 10; ++v) acc[v] += partials[b * 10 + v];
  }
#pragma unroll
  for (int off = 32; off > 0; off >>= 1) {
#pragma unroll
    for (int v = 0; v < 10; ++v) acc[v] += __shfl_down(acc[v], off, 64);
  }
  __shared__ float lds[4][10];
  const int lane = threadIdx.x & 63;
  const int wave = threadIdx.x >> 6;
  if (lane == 0) {
#pragma unroll
    for (int v = 0; v < 10; ++v) lds[wave][v] = acc[v];
  }
  __syncthreads();
  if (threadIdx.x == 0) {
    const float W[5] = {0.3f, 0.175f, 0.175f, 0.175f, 0.175f};
    float r = 0.f;
#pragma unroll
    for (int c = 0; c < 5; ++c) {
      float sc = lds[0][c] + lds[1][c] + lds[2][c] + lds[3][c];
      float ac = lds[0][5 + c] + lds[1][5 + c] + lds[2][5 + c] + lds[3][5 + c];
      r += W[c] * ac / sc;
    }
    *out = r;
  }
}

extern "C" void kernel_launch(void* const* d_in, const int* in_sizes, int n_in,
                              void* d_out, int out_size, void* d_ws, size_t ws_size,
                              hipStream_t stream) {
  const float* yt = (const float*)d_in[0];
  const float* yp = (const float*)d_in[1];
  const long long nelem = (long long)in_sizes[0];
  const long long nrows = nelem / 5;
  float* partials = (float*)d_ws;  // GRID * 10 floats = 80 KB

  if (nelem == (long long)TTH * KLOADS * 4) {
    regress_reduce_fast<<<GRID, BLOCK, 0, stream>>>(yt, yp, partials);
  } else {
    regress_reduce_generic<<<GRID, BLOCK, 0, stream>>>(yt, yp, partials, nrows);
  }
  regress_finalize<<<1, 256, 0, stream>>>(partials, GRID, (float*)d_out);
}